// Round 7
// baseline (332.089 us; speedup 1.0000x reference)
//
#include <hip/hip_runtime.h>
#include <stdint.h>
#include <stddef.h>

#define C_DIM 248
#define N_KP 512
#define HW_PIX 65536
#define NWIN 4
#define NTILE 32             // 512 kp / 16 per tile
#define GROUPS 512           // 128-px groups per window
#define SCALE_LOG2 144.2695041f   // 100 * log2(e)

typedef __attribute__((ext_vector_type(8))) short bf16x8;
typedef __attribute__((ext_vector_type(4))) float f32x4;

__device__ __forceinline__ unsigned short f32_bf16(float f) {
    union { float f; uint32_t u; } x; x.f = f;
    uint32_t r = x.u + 0x7FFFu + ((x.u >> 16) & 1u);
    return (unsigned short)(r >> 16);
}
__device__ __forceinline__ float bf16_f32(unsigned short h) {
    union { uint32_t u; float f; } x; x.u = ((uint32_t)h) << 16;
    return x.f;
}
__device__ __forceinline__ float fexp2(float x) {
    return __builtin_amdgcn_exp2f(x);
}

// ---------- Kernel 1: kp desc -> tile-contiguous bf16 hi/lo fragments ----------
// Tile (b,t) = 1024 frags of 16B (16 KB): hi half frag[kk*64 + l4*16 + c15],
// lo half at +512. Frag (c15,l4,kk) = 8 bf16 for k = kk*32 + l4*8 + j, col=t*16+c15.
__global__ __launch_bounds__(256) void k_prep(const float* __restrict__ kd,
                                              bf16x8* __restrict__ Bws) {
    int g = blockIdx.x * 256 + threadIdx.x;       // 65536 threads
    int c15 = g & 15;
    int l4 = (g >> 4) & 3;
    int kk = (g >> 6) & 7;
    int t  = (g >> 9) & 31;
    int b  = g >> 14;
    int col = t * 16 + c15;
    const float* base = kd + (size_t)(2 * b + 1) * C_DIM * N_KP;
    bf16x8 hi, lo;
    #pragma unroll
    for (int j = 0; j < 8; ++j) {
        int c = kk * 32 + l4 * 8 + j;
        float v = (c < C_DIM) ? base[(size_t)c * N_KP + col] : 0.0f;
        unsigned short hb = f32_bf16(v);
        float rlo = v - bf16_f32(hb);
        hi[j] = (short)hb;
        lo[j] = (short)f32_bf16(rlo);
    }
    size_t tb = (size_t)(b * 32 + t) * 1024 + kk * 64 + l4 * 16 + c15;
    Bws[tb] = hi;
    Bws[tb + 512] = lo;
}

// ---------- Kernel 2: A-in-regs, B LDS 4-slot, 2-tile pipelined ----------
// grid: 4 win x 512 groups (128 px); block 256 = 4 waves x 32 px
__global__ __launch_bounds__(256, 2) void k_main(const float* __restrict__ dd,
                                                 const bf16x8* __restrict__ Bws,
                                                 float4* __restrict__ partials) {
    int b = blockIdx.x >> 9;
    int grp = blockIdx.x & 511;
    int tid = threadIdx.x;
    int lane = tid & 63;
    int wave = tid >> 6;
    int l15 = lane & 15;
    int l4 = lane >> 4;
    int pw = grp * 128 + wave * 32;

    __shared__ __align__(16) short Bbuf[4][8192];   // 4 x 16 KB B-tile slots
    __shared__ float4 Wst[4][4][128];               // 8 KB per-wave partial buffer

    const bf16x8* Btile_base = Bws + (size_t)b * 32 * 1024;
    #define STAGE(slot_, t_)                                                          \
        {                                                                             \
            const bf16x8* src_ = Btile_base + (size_t)(t_) * 1024;                    \
            _Pragma("unroll")                                                         \
            for (int i_ = 0; i_ < 4; ++i_) {                                          \
                __builtin_amdgcn_global_load_lds(                                     \
                    (const __attribute__((address_space(1))) void*)                   \
                        (src_ + (i_ * 4 + wave) * 64 + lane),                         \
                    (__attribute__((address_space(3))) void*)                         \
                        ((char*)&Bbuf[slot_][0] + (i_ * 4 + wave) * 1024),            \
                    16, 0, 0);                                                        \
            }                                                                         \
        }

    STAGE(0, 0)
    STAGE(1, 1)

    // ---- A: 32 px x 256 k in regs (hi/lo), fused norm (overlaps stage latency) ----
    const float* srcp = dd + (size_t)(2 * b) * C_DIM * HW_PIX;
    bf16x8 aH[2][8], aL[2][8];
    float ss[2] = {0.f, 0.f};
    #pragma unroll
    for (int s = 0; s < 2; ++s) {
        #pragma unroll
        for (int kk = 0; kk < 8; ++kk) {
            #pragma unroll
            for (int j = 0; j < 8; ++j) {
                int c = kk * 32 + l4 * 8 + j;
                float v = (c < C_DIM) ? srcp[(size_t)c * HW_PIX + pw + s * 16 + l15] : 0.0f;
                ss[s] = fmaf(v, v, ss[s]);
                unsigned short hb = f32_bf16(v);
                float rlo = v - bf16_f32(hb);
                aH[s][kk][j] = (short)hb;
                aL[s][kk][j] = (short)f32_bf16(rlo);
            }
        }
        ss[s] += __shfl_xor(ss[s], 16);
        ss[s] += __shfl_xor(ss[s], 32);            // full 248-sum for pixel pw+s*16+l15
    }
    // srow in exp2 domain; uu = u coordinate of this lane's 8 rows
    float srow[2][4], uu[2][4];
    #pragma unroll
    for (int s = 0; s < 2; ++s) {
        #pragma unroll
        for (int r = 0; r < 4; ++r) {
            float ssr = __shfl(ss[s], l4 * 4 + r);
            srow[s][r] = SCALE_LOG2 / fmaxf(sqrtf(ssr), 1e-12f);
            uu[s][r] = (float)((pw & 255) + s * 16 + l4 * 4 + r);
        }
    }

    // per-tile per-lane softmax partial (8 px rows) -> Wst; no cross-lane, no barrier
    auto do_tile = [&](f32x4 (&ac)[2][3], int t) {
        float lg[2][4];
        float m = -3.0e38f;
        #pragma unroll
        for (int s = 0; s < 2; ++s)
            #pragma unroll
            for (int r = 0; r < 4; ++r) {
                lg[s][r] = (ac[s][0][r] + ac[s][1][r] + ac[s][2][r]) * srow[s][r];
                m = fmaxf(m, lg[s][r]);
            }
        float d = 0.f, sx = 0.f;
        #pragma unroll
        for (int s = 0; s < 2; ++s)
            #pragma unroll
            for (int r = 0; r < 4; ++r) {
                float e = fexp2(lg[s][r] - m);
                d += e;
                sx = fmaf(e, uu[s][r], sx);
            }
        float4 p; p.x = m; p.y = d; p.z = sx; p.w = 0.f;
        Wst[wave][l4][(t & 7) * 16 + l15] = p;
    };

    for (int p = 0; p < NTILE / 2; ++p) {
        int t = 2 * p;
        // own stage(t)/stage(t+1) loads land before barrier -> barrier certifies
        // all waves' slot-t/t+1 bytes present (race-free)
        asm volatile("s_waitcnt vmcnt(0)" ::: "memory");
        __builtin_amdgcn_s_barrier();
        if (t + 2 < NTILE) STAGE((t + 2) & 3, t + 2)
        if (t + 3 < NTILE) STAGE((t + 3) & 3, t + 3)

        const bf16x8* B0 = (const bf16x8*)&Bbuf[t & 3][0];
        const bf16x8* B1 = (const bf16x8*)&Bbuf[(t + 1) & 3][0];
        f32x4 acA[2][3], acB[2][3];
        #pragma unroll
        for (int s = 0; s < 2; ++s)
            #pragma unroll
            for (int q = 0; q < 3; ++q) {
                acA[s][q] = (f32x4){0.f, 0.f, 0.f, 0.f};
                acB[s][q] = (f32x4){0.f, 0.f, 0.f, 0.f};
            }

        __builtin_amdgcn_s_setprio(1);
        #pragma unroll
        for (int kk = 0; kk < 8; ++kk) {
            bf16x8 bH = B0[kk * 64 + lane];
            bf16x8 bL = B0[512 + kk * 64 + lane];
            acA[0][0] = __builtin_amdgcn_mfma_f32_16x16x32_bf16(aH[0][kk], bH, acA[0][0], 0, 0, 0);
            acA[1][0] = __builtin_amdgcn_mfma_f32_16x16x32_bf16(aH[1][kk], bH, acA[1][0], 0, 0, 0);
            acA[0][1] = __builtin_amdgcn_mfma_f32_16x16x32_bf16(aH[0][kk], bL, acA[0][1], 0, 0, 0);
            acA[1][1] = __builtin_amdgcn_mfma_f32_16x16x32_bf16(aH[1][kk], bL, acA[1][1], 0, 0, 0);
            acA[0][2] = __builtin_amdgcn_mfma_f32_16x16x32_bf16(aL[0][kk], bH, acA[0][2], 0, 0, 0);
            acA[1][2] = __builtin_amdgcn_mfma_f32_16x16x32_bf16(aL[1][kk], bH, acA[1][2], 0, 0, 0);
        }
        #pragma unroll
        for (int kk = 0; kk < 8; ++kk) {
            bf16x8 bH = B1[kk * 64 + lane];
            bf16x8 bL = B1[512 + kk * 64 + lane];
            acB[0][0] = __builtin_amdgcn_mfma_f32_16x16x32_bf16(aH[0][kk], bH, acB[0][0], 0, 0, 0);
            acB[1][0] = __builtin_amdgcn_mfma_f32_16x16x32_bf16(aH[1][kk], bH, acB[1][0], 0, 0, 0);
            acB[0][1] = __builtin_amdgcn_mfma_f32_16x16x32_bf16(aH[0][kk], bL, acB[0][1], 0, 0, 0);
            acB[1][1] = __builtin_amdgcn_mfma_f32_16x16x32_bf16(aH[1][kk], bL, acB[1][1], 0, 0, 0);
            acB[0][2] = __builtin_amdgcn_mfma_f32_16x16x32_bf16(aL[0][kk], bH, acB[0][2], 0, 0, 0);
            acB[1][2] = __builtin_amdgcn_mfma_f32_16x16x32_bf16(aL[1][kk], bH, acB[1][2], 0, 0, 0);
        }
        __builtin_amdgcn_s_setprio(0);

        do_tile(acA, t);
        do_tile(acB, t + 1);

        if (((t + 1) & 7) == 7) {                    // merge 16 partials -> global
            __syncthreads();
            if (tid < 128) {
                float4 s0 = Wst[0][0][tid];
                float M = s0.x, D = s0.y, SX = s0.z;
                #pragma unroll
                for (int sIdx = 1; sIdx < 16; ++sIdx) {
                    float4 q = Wst[sIdx >> 2][sIdx & 3][tid];
                    float Mn = fmaxf(M, q.x);
                    float c1 = fexp2(M - Mn);
                    float c2 = fexp2(q.x - Mn);
                    D  = D  * c1 + q.y * c2;
                    SX = SX * c1 + q.z * c2;
                    M = Mn;
                }
                float4 o; o.x = M; o.y = D; o.z = SX; o.w = 0.f;
                partials[((size_t)b * GROUPS + grp) * 512 + (t >> 3) * 128 + tid] = o;
            }
            __syncthreads();
        }
    }
    #undef STAGE
}

// ---------- Kernel 3: reduce 512 group-partials per (b,kp); sy = v(g)*d ----------
__global__ __launch_bounds__(256) void k_reduce(const float4* __restrict__ partials,
                                                const float* __restrict__ ksc,
                                                float* __restrict__ out) {
    int b = blockIdx.x >> 5;
    int kc = blockIdx.x & 31;
    int tid = threadIdx.x;
    int kpo = tid & 15;
    int gs = tid >> 4;
    int kp = kc * 16 + kpo;

    float M = -1e30f, D = 0.f, SX = 0.f, SY = 0.f;
    for (int g = gs; g < GROUPS; g += 16) {
        float4 p = partials[((size_t)b * GROUPS + g) * 512 + kp];
        float vg = (float)(g >> 1);                 // v constant per 128-px group
        float Mn = fmaxf(M, p.x);
        float c1 = fexp2(M - Mn);
        float c2 = fexp2(p.x - Mn);
        D  = D  * c1 + p.y * c2;
        SX = SX * c1 + p.z * c2;
        SY = SY * c1 + vg * p.y * c2;
        M = Mn;
    }
    __shared__ float4 red[16][16];
    float4 me; me.x = M; me.y = D; me.z = SX; me.w = SY;
    red[gs][kpo] = me;
    __syncthreads();
    if (gs == 0) {
        #pragma unroll
        for (int w = 1; w < 16; ++w) {
            float4 p = red[w][kpo];
            float Mn = fmaxf(M, p.x);
            float c1 = fexp2(M - Mn);
            float c2 = fexp2(p.x - Mn);
            D  = D  * c1 + p.y * c2;
            SX = SX * c1 + p.z * c2;
            SY = SY * c1 + p.w * c2;
            M = Mn;
        }
        int flat = b * 512 + kp;
        out[flat * 2 + 0] = SX / D;
        out[flat * 2 + 1] = SY / D;
        out[4096 + flat] = ksc[(size_t)(2 * b + 1) * N_KP + kp];
    }
    if (blockIdx.x == 0 && tid < 4) out[6144 + tid] = (float)(2 * tid + 1);
}

extern "C" void kernel_launch(void* const* d_in, const int* in_sizes, int n_in,
                              void* d_out, int out_size, void* d_ws, size_t ws_size,
                              hipStream_t stream) {
    const float* kp_scores  = (const float*)d_in[0];
    const float* kp_desc    = (const float*)d_in[1];
    const float* desc_dense = (const float*)d_in[3];
    float* out = (float*)d_out;

    // ws: Bws 2 MB | partials 16 MB
    bf16x8* Bws = (bf16x8*)d_ws;
    float4* partials = (float4*)((char*)d_ws + (size_t)NWIN * 32 * 1024 * 16);

    k_prep<<<256, 256, 0, stream>>>(kp_desc, Bws);
    k_main<<<NWIN * GROUPS, 256, 0, stream>>>(desc_dense, Bws, partials);
    k_reduce<<<NWIN * 32, 256, 0, stream>>>(partials, kp_scores, out);
}

// Round 8
// 259.941 us; speedup vs baseline: 1.2776x; 1.2776x over previous
//
#include <hip/hip_runtime.h>
#include <stdint.h>
#include <stddef.h>

#define C_DIM 248
#define N_KP 512
#define HW_PIX 65536
#define NWIN 4
#define NTILE 32             // 512 kp / 16 per tile
#define GROUPS 512           // 128-px groups per window
#define SCALE_LOG2 144.2695041f   // 100 * log2(e)

typedef __attribute__((ext_vector_type(8))) short bf16x8;
typedef __attribute__((ext_vector_type(4))) float f32x4;

__device__ __forceinline__ unsigned short f32_bf16(float f) {
    union { float f; uint32_t u; } x; x.f = f;
    uint32_t r = x.u + 0x7FFFu + ((x.u >> 16) & 1u);
    return (unsigned short)(r >> 16);
}
__device__ __forceinline__ float bf16_f32(unsigned short h) {
    union { uint32_t u; float f; } x; x.u = ((uint32_t)h) << 16;
    return x.f;
}
__device__ __forceinline__ float fexp2(float x) {
    return __builtin_amdgcn_exp2f(x);
}

// ---------- Kernel 1: kp desc -> tile-contiguous bf16 hi/lo fragments ----------
// Tile (b,t) = 1024 frags of 16B (16 KB): hi half frag[kk*64 + l4*16 + c15],
// lo half at +512. Frag (c15,l4,kk) = 8 bf16 for k = kk*32 + l4*8 + j, col=t*16+c15.
__global__ __launch_bounds__(256) void k_prep(const float* __restrict__ kd,
                                              bf16x8* __restrict__ Bws) {
    int g = blockIdx.x * 256 + threadIdx.x;       // 65536 threads
    int c15 = g & 15;
    int l4 = (g >> 4) & 3;
    int kk = (g >> 6) & 7;
    int t  = (g >> 9) & 31;
    int b  = g >> 14;
    int col = t * 16 + c15;
    const float* base = kd + (size_t)(2 * b + 1) * C_DIM * N_KP;
    bf16x8 hi, lo;
    #pragma unroll
    for (int j = 0; j < 8; ++j) {
        int c = kk * 32 + l4 * 8 + j;
        float v = (c < C_DIM) ? base[(size_t)c * N_KP + col] : 0.0f;
        unsigned short hb = f32_bf16(v);
        float rlo = v - bf16_f32(hb);
        hi[j] = (short)hb;
        lo[j] = (short)f32_bf16(rlo);
    }
    size_t tb = (size_t)(b * 32 + t) * 1024 + kk * 64 + l4 * 16 + c15;
    Bws[tb] = hi;
    Bws[tb + 512] = lo;
}

// ---------- Kernel 2: A-in-regs, B LDS 4-slot, 2-tile pipelined, 72 KB LDS ----------
// grid: 4 win x 512 groups (128 px); block 256 = 4 waves x 32 px
__global__ __launch_bounds__(256, 2) void k_main(const float* __restrict__ dd,
                                                 const bf16x8* __restrict__ Bws,
                                                 float4* __restrict__ partials) {
    int b = blockIdx.x >> 9;
    int grp = blockIdx.x & 511;
    int tid = threadIdx.x;
    int lane = tid & 63;
    int wave = tid >> 6;
    int l15 = lane & 15;
    int l4 = lane >> 4;
    int pw = grp * 128 + wave * 32;

    __shared__ __align__(16) short Bbuf[4][8192];   // 4 x 16 KB B-tile slots
    __shared__ float4 Wst[4][8][16];                // 8 KB: [wave][tile&7][kp15]

    const bf16x8* Btile_base = Bws + (size_t)b * 32 * 1024;
    #define STAGE(slot_, t_)                                                          \
        {                                                                             \
            const bf16x8* src_ = Btile_base + (size_t)(t_) * 1024;                    \
            _Pragma("unroll")                                                         \
            for (int i_ = 0; i_ < 4; ++i_) {                                          \
                __builtin_amdgcn_global_load_lds(                                     \
                    (const __attribute__((address_space(1))) void*)                   \
                        (src_ + (i_ * 4 + wave) * 64 + lane),                         \
                    (__attribute__((address_space(3))) void*)                         \
                        ((char*)&Bbuf[slot_][0] + (i_ * 4 + wave) * 1024),            \
                    16, 0, 0);                                                        \
            }                                                                         \
        }

    STAGE(0, 0)
    STAGE(1, 1)

    // ---- A: 32 px x 256 k in regs (hi/lo), fused norm (overlaps stage latency) ----
    const float* srcp = dd + (size_t)(2 * b) * C_DIM * HW_PIX;
    bf16x8 aH[2][8], aL[2][8];
    float ss[2] = {0.f, 0.f};
    #pragma unroll
    for (int s = 0; s < 2; ++s) {
        #pragma unroll
        for (int kk = 0; kk < 8; ++kk) {
            #pragma unroll
            for (int j = 0; j < 8; ++j) {
                int c = kk * 32 + l4 * 8 + j;
                float v = (c < C_DIM) ? srcp[(size_t)c * HW_PIX + pw + s * 16 + l15] : 0.0f;
                ss[s] = fmaf(v, v, ss[s]);
                unsigned short hb = f32_bf16(v);
                float rlo = v - bf16_f32(hb);
                aH[s][kk][j] = (short)hb;
                aL[s][kk][j] = (short)f32_bf16(rlo);
            }
        }
        ss[s] += __shfl_xor(ss[s], 16);
        ss[s] += __shfl_xor(ss[s], 32);            // full 248-sum for pixel pw+s*16+l15
    }
    // srow in exp2 domain; uu = u coordinate of this lane's 8 rows
    float srow[2][4], uu[2][4];
    #pragma unroll
    for (int s = 0; s < 2; ++s) {
        #pragma unroll
        for (int r = 0; r < 4; ++r) {
            float ssr = __shfl(ss[s], l4 * 4 + r);
            srow[s][r] = SCALE_LOG2 / fmaxf(sqrtf(ssr), 1e-12f);
            uu[s][r] = (float)((pw & 255) + s * 16 + l4 * 4 + r);
        }
    }

    // per-tile: per-lane partial over 8 px rows, l4-merge in-wave, lanes0-15 -> Wst
    auto do_tile = [&](f32x4 (&ac)[2][3], int t) {
        float lg[2][4];
        float m = -3.0e38f;
        #pragma unroll
        for (int s = 0; s < 2; ++s)
            #pragma unroll
            for (int r = 0; r < 4; ++r) {
                lg[s][r] = (ac[s][0][r] + ac[s][1][r] + ac[s][2][r]) * srow[s][r];
                m = fmaxf(m, lg[s][r]);
            }
        float d = 0.f, sx = 0.f;
        #pragma unroll
        for (int s = 0; s < 2; ++s)
            #pragma unroll
            for (int r = 0; r < 4; ++r) {
                float e = fexp2(lg[s][r] - m);
                d += e;
                sx = fmaf(e, uu[s][r], sx);
            }
        #pragma unroll
        for (int off = 16; off <= 32; off <<= 1) {   // merge the 4 l4 row-groups
            float m2 = __shfl_xor(m, off);
            float d2 = __shfl_xor(d, off);
            float sx2 = __shfl_xor(sx, off);
            float Mn = fmaxf(m, m2);
            float c1 = fexp2(m - Mn);
            float c2 = fexp2(m2 - Mn);
            d  = d * c1 + d2 * c2;
            sx = sx * c1 + sx2 * c2;
            m = Mn;
        }
        if (lane < 16) {
            float4 p; p.x = m; p.y = d; p.z = sx; p.w = 0.f;
            Wst[wave][t & 7][l15] = p;
        }
    };

    for (int p = 0; p < NTILE / 2; ++p) {
        int t = 2 * p;
        // own stage(t)/stage(t+1) loads land before barrier -> barrier certifies
        // all waves' slot-t/t+1 bytes present (race-free)
        asm volatile("s_waitcnt vmcnt(0)" ::: "memory");
        __builtin_amdgcn_s_barrier();
        if (t + 2 < NTILE) STAGE((t + 2) & 3, t + 2)
        if (t + 3 < NTILE) STAGE((t + 3) & 3, t + 3)

        const bf16x8* B0 = (const bf16x8*)&Bbuf[t & 3][0];
        const bf16x8* B1 = (const bf16x8*)&Bbuf[(t + 1) & 3][0];
        f32x4 acA[2][3], acB[2][3];
        #pragma unroll
        for (int s = 0; s < 2; ++s)
            #pragma unroll
            for (int q = 0; q < 3; ++q) {
                acA[s][q] = (f32x4){0.f, 0.f, 0.f, 0.f};
                acB[s][q] = (f32x4){0.f, 0.f, 0.f, 0.f};
            }

        __builtin_amdgcn_s_setprio(1);
        #pragma unroll
        for (int kk = 0; kk < 8; ++kk) {
            bf16x8 bH = B0[kk * 64 + lane];
            bf16x8 bL = B0[512 + kk * 64 + lane];
            acA[0][0] = __builtin_amdgcn_mfma_f32_16x16x32_bf16(aH[0][kk], bH, acA[0][0], 0, 0, 0);
            acA[1][0] = __builtin_amdgcn_mfma_f32_16x16x32_bf16(aH[1][kk], bH, acA[1][0], 0, 0, 0);
            acA[0][1] = __builtin_amdgcn_mfma_f32_16x16x32_bf16(aH[0][kk], bL, acA[0][1], 0, 0, 0);
            acA[1][1] = __builtin_amdgcn_mfma_f32_16x16x32_bf16(aH[1][kk], bL, acA[1][1], 0, 0, 0);
            acA[0][2] = __builtin_amdgcn_mfma_f32_16x16x32_bf16(aL[0][kk], bH, acA[0][2], 0, 0, 0);
            acA[1][2] = __builtin_amdgcn_mfma_f32_16x16x32_bf16(aL[1][kk], bH, acA[1][2], 0, 0, 0);
        }
        #pragma unroll
        for (int kk = 0; kk < 8; ++kk) {
            bf16x8 bH = B1[kk * 64 + lane];
            bf16x8 bL = B1[512 + kk * 64 + lane];
            acB[0][0] = __builtin_amdgcn_mfma_f32_16x16x32_bf16(aH[0][kk], bH, acB[0][0], 0, 0, 0);
            acB[1][0] = __builtin_amdgcn_mfma_f32_16x16x32_bf16(aH[1][kk], bH, acB[1][0], 0, 0, 0);
            acB[0][1] = __builtin_amdgcn_mfma_f32_16x16x32_bf16(aH[0][kk], bL, acB[0][1], 0, 0, 0);
            acB[1][1] = __builtin_amdgcn_mfma_f32_16x16x32_bf16(aH[1][kk], bL, acB[1][1], 0, 0, 0);
            acB[0][2] = __builtin_amdgcn_mfma_f32_16x16x32_bf16(aL[0][kk], bH, acB[0][2], 0, 0, 0);
            acB[1][2] = __builtin_amdgcn_mfma_f32_16x16x32_bf16(aL[1][kk], bH, acB[1][2], 0, 0, 0);
        }
        __builtin_amdgcn_s_setprio(0);

        do_tile(acA, t);
        do_tile(acB, t + 1);

        if (((t + 1) & 7) == 7) {                    // merge 4 waves x 8 tiles -> global
            __syncthreads();
            if (tid < 128) {                          // tid = tslot*16 + kp15
                int tslot = tid >> 4;
                int kp15 = tid & 15;
                float4 s0 = Wst[0][tslot][kp15];
                float M = s0.x, D = s0.y, SX = s0.z;
                #pragma unroll
                for (int w = 1; w < 4; ++w) {
                    float4 q = Wst[w][tslot][kp15];
                    float Mn = fmaxf(M, q.x);
                    float c1 = fexp2(M - Mn);
                    float c2 = fexp2(q.x - Mn);
                    D  = D  * c1 + q.y * c2;
                    SX = SX * c1 + q.z * c2;
                    M = Mn;
                }
                float4 o; o.x = M; o.y = D; o.z = SX; o.w = 0.f;
                partials[((size_t)b * GROUPS + grp) * 512 + (t >> 3) * 128 + tid] = o;
            }
            __syncthreads();
        }
    }
    #undef STAGE
}

// ---------- Kernel 3: reduce 512 group-partials per (b,kp); sy = v(g)*d ----------
__global__ __launch_bounds__(256) void k_reduce(const float4* __restrict__ partials,
                                                const float* __restrict__ ksc,
                                                float* __restrict__ out) {
    int b = blockIdx.x >> 5;
    int kc = blockIdx.x & 31;
    int tid = threadIdx.x;
    int kpo = tid & 15;
    int gs = tid >> 4;
    int kp = kc * 16 + kpo;

    float M = -1e30f, D = 0.f, SX = 0.f, SY = 0.f;
    for (int g = gs; g < GROUPS; g += 16) {
        float4 p = partials[((size_t)b * GROUPS + g) * 512 + kp];
        float vg = (float)(g >> 1);                 // v constant per 128-px group
        float Mn = fmaxf(M, p.x);
        float c1 = fexp2(M - Mn);
        float c2 = fexp2(p.x - Mn);
        D  = D  * c1 + p.y * c2;
        SX = SX * c1 + p.z * c2;
        SY = SY * c1 + vg * p.y * c2;
        M = Mn;
    }
    __shared__ float4 red[16][16];
    float4 me; me.x = M; me.y = D; me.z = SX; me.w = SY;
    red[gs][kpo] = me;
    __syncthreads();
    if (gs == 0) {
        #pragma unroll
        for (int w = 1; w < 16; ++w) {
            float4 p = red[w][kpo];
            float Mn = fmaxf(M, p.x);
            float c1 = fexp2(M - Mn);
            float c2 = fexp2(p.x - Mn);
            D  = D  * c1 + p.y * c2;
            SX = SX * c1 + p.z * c2;
            SY = SY * c1 + p.w * c2;
            M = Mn;
        }
        int flat = b * 512 + kp;
        out[flat * 2 + 0] = SX / D;
        out[flat * 2 + 1] = SY / D;
        out[4096 + flat] = ksc[(size_t)(2 * b + 1) * N_KP + kp];
    }
    if (blockIdx.x == 0 && tid < 4) out[6144 + tid] = (float)(2 * tid + 1);
}

extern "C" void kernel_launch(void* const* d_in, const int* in_sizes, int n_in,
                              void* d_out, int out_size, void* d_ws, size_t ws_size,
                              hipStream_t stream) {
    const float* kp_scores  = (const float*)d_in[0];
    const float* kp_desc    = (const float*)d_in[1];
    const float* desc_dense = (const float*)d_in[3];
    float* out = (float*)d_out;

    // ws: Bws 2 MB | partials 16 MB
    bf16x8* Bws = (bf16x8*)d_ws;
    float4* partials = (float4*)((char*)d_ws + (size_t)NWIN * 32 * 1024 * 16);

    k_prep<<<256, 256, 0, stream>>>(kp_desc, Bws);
    k_main<<<NWIN * GROUPS, 256, 0, stream>>>(desc_dense, Bws, partials);
    k_reduce<<<NWIN * 32, 256, 0, stream>>>(partials, kp_scores, out);
}